// Round 2
// baseline (3038.226 us; speedup 1.0000x reference)
//
#include <hip/hip_runtime.h>

#define N_ROWS 8192
#define M_ROWS 4096
#define D_DIM  512
#define N_ITERS 100
constexpr size_t NM = (size_t)N_ROWS * (size_t)M_ROWS;
constexpr float FREG   = 0.1f;
constexpr float FI     = 0.5f / (0.5f + 0.1f);     // tau/(tau+reg)
constexpr float A_MARG = 1.0f / (float)N_ROWS;
constexpr float B_MARG = 1.0f / (float)M_ROWS;

// ---------- bf16 helpers (RNE pack) ----------
__device__ __forceinline__ unsigned short f2bf(float f) {
    unsigned int u = __float_as_uint(f);
    u += 0x7fffu + ((u >> 16) & 1u);
    return (unsigned short)(u >> 16);
}
__device__ __forceinline__ float bflo(unsigned int u) { return __uint_as_float(u << 16); }
__device__ __forceinline__ float bfhi(unsigned int u) { return __uint_as_float(u & 0xffff0000u); }
__device__ __forceinline__ unsigned int pack2(float a, float b) {
    return (unsigned int)f2bf(a) | ((unsigned int)f2bf(b) << 16);
}

// ---------- K0: init v = 1/m, maxc = 0, dist = 0 ----------
__global__ void __launch_bounds__(256) init_kernel(float* v, unsigned int* maxc, float* dist) {
    int t = blockIdx.x * 256 + threadIdx.x;
    if (t < M_ROWS) v[t] = B_MARG;
    if (t == 0) { *maxc = 0u; *dist = 0.0f; }
}

// ---------- K1: per-row min-shift + bf16 cast + sum of squares ----------
__global__ void __launch_bounds__(256) rownorm_kernel(const float* __restrict__ x,
                                                      unsigned short* __restrict__ xn,
                                                      float* __restrict__ x2) {
    int lane = threadIdx.x & 63;
    int row  = blockIdx.x * 4 + (threadIdx.x >> 6);
    const float* p = x + (size_t)row * D_DIM + lane * 8;
    float4 v0 = *(const float4*)p;
    float4 v1 = *(const float4*)(p + 4);
    float a[8] = {v0.x, v0.y, v0.z, v0.w, v1.x, v1.y, v1.z, v1.w};
    float mn = a[0];
#pragma unroll
    for (int t = 1; t < 8; ++t) mn = fminf(mn, a[t]);
#pragma unroll
    for (int o = 32; o >= 1; o >>= 1) mn = fminf(mn, __shfl_xor(mn, o, 64));
    float ss = 0.0f;
#pragma unroll
    for (int t = 0; t < 8; ++t) { a[t] -= mn; ss = fmaf(a[t], a[t], ss); }
#pragma unroll
    for (int o = 32; o >= 1; o >>= 1) ss += __shfl_xor(ss, o, 64);
    uint4 pk;
    pk.x = pack2(a[0], a[1]); pk.y = pack2(a[2], a[3]);
    pk.z = pack2(a[4], a[5]); pk.w = pack2(a[6], a[7]);
    *(uint4*)(xn + (size_t)row * D_DIM + lane * 8) = pk;
    if (lane == 0) x2[row] = ss;
}

// ---------- K2: bf16 MFMA GEMM -> cost (bf16, row-major N x M) + global max ----------
typedef __attribute__((ext_vector_type(8))) short short8;   // 8 bf16 = 4 VGPRs
typedef __attribute__((ext_vector_type(4))) float f32x4;

__global__ void __launch_bounds__(256) gemm_cost_kernel(const unsigned short* __restrict__ xn,
                                                        const unsigned short* __restrict__ yn,
                                                        const float* __restrict__ x2,
                                                        const float* __restrict__ y2,
                                                        unsigned short* __restrict__ cost,
                                                        unsigned int* __restrict__ maxc) {
    // 128x128 block tile, 4 waves in 2x2, each wave 64x64 via 4x4 MFMA 16x16x32
    __shared__ unsigned short As[128 * 40];   // pad 32->40 to break bank conflicts
    __shared__ unsigned short Bs[128 * 40];
    __shared__ float wred[4];
    int tid = threadIdx.x, lane = tid & 63, w = tid >> 6;
    int wm = w >> 1, wn = w & 1;
    int i0 = blockIdx.x * 128, j0 = blockIdx.y * 128;
    int lr = tid >> 2;      // 0..63 (staging row)
    int lq = tid & 3;       // 0..3  (staging col group of 8)
    f32x4 acc[4][4] = {};
    int m = lane & 15, quad = lane >> 4;

    for (int k0 = 0; k0 < D_DIM; k0 += 32) {
        uint4 a0 = *(const uint4*)(xn + (size_t)(i0 + lr) * D_DIM + k0 + lq * 8);
        uint4 a1 = *(const uint4*)(xn + (size_t)(i0 + lr + 64) * D_DIM + k0 + lq * 8);
        uint4 b0 = *(const uint4*)(yn + (size_t)(j0 + lr) * D_DIM + k0 + lq * 8);
        uint4 b1 = *(const uint4*)(yn + (size_t)(j0 + lr + 64) * D_DIM + k0 + lq * 8);
        __syncthreads();
        *(uint4*)&As[lr * 40 + lq * 8]        = a0;
        *(uint4*)&As[(lr + 64) * 40 + lq * 8] = a1;
        *(uint4*)&Bs[lr * 40 + lq * 8]        = b0;
        *(uint4*)&Bs[(lr + 64) * 40 + lq * 8] = b1;
        __syncthreads();
        short8 af[4], bfr[4];
#pragma unroll
        for (int t = 0; t < 4; ++t) {
            af[t]  = *(const short8*)&As[(wm * 64 + t * 16 + m) * 40 + quad * 8];
            bfr[t] = *(const short8*)&Bs[(wn * 64 + t * 16 + m) * 40 + quad * 8];
        }
#pragma unroll
        for (int tm = 0; tm < 4; ++tm)
#pragma unroll
            for (int tn = 0; tn < 4; ++tn)
                acc[tm][tn] = __builtin_amdgcn_mfma_f32_16x16x32_bf16(af[tm], bfr[tn], acc[tm][tn], 0, 0, 0);
    }

    // epilogue: C/D layout col=lane&15, row=(lane>>4)*4+reg  [m89/m91 verified]
    float mymax = 0.0f;
#pragma unroll
    for (int tm = 0; tm < 4; ++tm) {
#pragma unroll
        for (int tn = 0; tn < 4; ++tn) {
            int col = j0 + wn * 64 + tn * 16 + m;
            float yv = y2[col];
#pragma unroll
            for (int t = 0; t < 4; ++t) {
                int row = i0 + wm * 64 + tm * 16 + quad * 4 + t;
                float c = fmaxf(x2[row] + yv - 2.0f * acc[tm][tn][t], 0.0f);
                mymax = fmaxf(mymax, c);
                cost[(size_t)row * M_ROWS + col] = f2bf(c);
            }
        }
    }
#pragma unroll
    for (int o = 32; o >= 1; o >>= 1) mymax = fmaxf(mymax, __shfl_xor(mymax, o, 64));
    if (lane == 0) wred[w] = mymax;
    __syncthreads();
    if (tid == 0) {
        float mx = fmaxf(fmaxf(wred[0], wred[1]), fmaxf(wred[2], wred[3]));
        atomicMax(maxc, __float_as_uint(mx));   // positive floats: uint order == float order
    }
}

// ---------- K3: K = exp(-cost*10/maxc) in place (bf16) + transposed copy KT ----------
__global__ void __launch_bounds__(256) expT_kernel(unsigned short* __restrict__ Kmat,
                                                   unsigned short* __restrict__ KTmat,
                                                   const unsigned int* __restrict__ maxcb) {
    __shared__ unsigned int tl[64 * 33];
    float scale = -(1.0f / FREG) / __uint_as_float(*maxcb);
    int i0 = blockIdx.x * 64, j0 = blockIdx.y * 64;
    int tid = threadIdx.x;
    int b = tid & 7;        // col group (8 cols)
    int rp = tid >> 3;      // 0..31 row pair
    size_t base0 = (size_t)(i0 + 2 * rp) * M_ROWS + j0 + b * 8;
    uint4 c0 = *(const uint4*)(Kmat + base0);
    uint4 c1 = *(const uint4*)(Kmat + base0 + M_ROWS);
    unsigned int cc0[4] = {c0.x, c0.y, c0.z, c0.w};
    unsigned int cc1[4] = {c1.x, c1.y, c1.z, c1.w};
    float k0[8], k1[8];
#pragma unroll
    for (int t = 0; t < 4; ++t) {
        k0[2 * t]     = expf(bflo(cc0[t]) * scale);
        k0[2 * t + 1] = expf(bfhi(cc0[t]) * scale);
        k1[2 * t]     = expf(bflo(cc1[t]) * scale);
        k1[2 * t + 1] = expf(bfhi(cc1[t]) * scale);
    }
    uint4 o0, o1;
    o0.x = pack2(k0[0], k0[1]); o0.y = pack2(k0[2], k0[3]);
    o0.z = pack2(k0[4], k0[5]); o0.w = pack2(k0[6], k0[7]);
    o1.x = pack2(k1[0], k1[1]); o1.y = pack2(k1[2], k1[3]);
    o1.z = pack2(k1[4], k1[5]); o1.w = pack2(k1[6], k1[7]);
    *(uint4*)(Kmat + base0)          = o0;   // in-place: tile-private addresses
    *(uint4*)(Kmat + base0 + M_ROWS) = o1;
#pragma unroll
    for (int t = 0; t < 8; ++t)
        tl[(b * 8 + t) * 33 + rp] = pack2(k0[t], k1[t]);  // T[c][row-pair], lo=even row
    __syncthreads();
    int c = tid >> 2, q = tid & 3;
    unsigned int o[8];
#pragma unroll
    for (int k = 0; k < 8; ++k) o[k] = tl[c * 33 + q * 8 + k];
    uint4 w0 = {o[0], o[1], o[2], o[3]};
    uint4 w1 = {o[4], o[5], o[6], o[7]};
    size_t ob = (size_t)(j0 + c) * N_ROWS + i0 + q * 16;
    *(uint4*)(KTmat + ob)     = w0;
    *(uint4*)(KTmat + ob + 8) = w1;
}

// ---------- K4a: u = (a / (K v))^fi   (one launch per half-iteration = grid sync) ----------
__global__ void __launch_bounds__(256) u_step_kernel(const unsigned short* __restrict__ Km,
                                                     const float* __restrict__ v,
                                                     float* __restrict__ u) {
    __shared__ __align__(16) float sv[M_ROWS];   // 16 KB
    int tid = threadIdx.x, lane = tid & 63, w = tid >> 6;
    for (int i = tid; i < M_ROWS / 4; i += 256)
        ((float4*)sv)[i] = ((const float4*)v)[i];
    __syncthreads();
#pragma unroll
    for (int rr = 0; rr < 2; ++rr) {
        int r = blockIdx.x * 8 + w * 2 + rr;
        const unsigned short* kp = Km + (size_t)r * M_ROWS;
        float dot = 0.0f;
#pragma unroll
        for (int s = 0; s < 16; ++s) {
            int j = s * 256 + lane * 4;
            uint2 kk = *(const uint2*)(kp + j);
            float4 vv = *(const float4*)(sv + j);
            dot = fmaf(bflo(kk.x), vv.x, dot);
            dot = fmaf(bfhi(kk.x), vv.y, dot);
            dot = fmaf(bflo(kk.y), vv.z, dot);
            dot = fmaf(bfhi(kk.y), vv.w, dot);
        }
#pragma unroll
        for (int o = 32; o >= 1; o >>= 1) dot += __shfl_xor(dot, o, 64);
        if (lane == 0) u[r] = powf(A_MARG / dot, FI);
    }
}

// ---------- K4b: v = (b / (K^T u))^fi ----------
__global__ void __launch_bounds__(256) v_step_kernel(const unsigned short* __restrict__ KTm,
                                                     const float* __restrict__ u,
                                                     float* __restrict__ v) {
    __shared__ __align__(16) float su[N_ROWS];   // 32 KB
    int tid = threadIdx.x, lane = tid & 63, w = tid >> 6;
    for (int i = tid; i < N_ROWS / 4; i += 256)
        ((float4*)su)[i] = ((const float4*)u)[i];
    __syncthreads();
#pragma unroll
    for (int rr = 0; rr < 2; ++rr) {
        int r = blockIdx.x * 8 + w * 2 + rr;
        const unsigned short* kp = KTm + (size_t)r * N_ROWS;
        float dot = 0.0f;
#pragma unroll
        for (int s = 0; s < 32; ++s) {
            int j = s * 256 + lane * 4;
            uint2 kk = *(const uint2*)(kp + j);
            float4 vv = *(const float4*)(su + j);
            dot = fmaf(bflo(kk.x), vv.x, dot);
            dot = fmaf(bfhi(kk.x), vv.y, dot);
            dot = fmaf(bflo(kk.y), vv.z, dot);
            dot = fmaf(bfhi(kk.y), vv.w, dot);
        }
#pragma unroll
        for (int o = 32; o >= 1; o >>= 1) dot += __shfl_xor(dot, o, 64);
        if (lane == 0) v[r] = powf(B_MARG / dot, FI);
    }
}

// ---------- K5: pi = flow^T (KT layout, coalesced), dist = sum(cost*flow) ----------
__global__ void __launch_bounds__(256) finalize_kernel(const unsigned short* __restrict__ KTm,
                                                       const float* __restrict__ u,
                                                       const float* __restrict__ v,
                                                       const unsigned int* __restrict__ maxcb,
                                                       float* __restrict__ out,
                                                       float* __restrict__ dist) {
    __shared__ float red[4];
    int tid = threadIdx.x, lane = tid & 63;
    size_t base = ((size_t)blockIdx.x * 256 + tid) * 8;
    int mrow = (int)(base >> 13);        // / 8192
    int n    = (int)(base & 8191);
    float cscale = -FREG * __uint_as_float(*maxcb);   // cost = -reg*maxc*ln(K)
    uint4 kk = *(const uint4*)(KTm + base);
    float4 u0 = *(const float4*)(u + n);
    float4 u1 = *(const float4*)(u + n + 4);
    float vm = v[mrow];
    float kv[8] = {bflo(kk.x), bfhi(kk.x), bflo(kk.y), bfhi(kk.y),
                   bflo(kk.z), bfhi(kk.z), bflo(kk.w), bfhi(kk.w)};
    float uu[8] = {u0.x, u0.y, u0.z, u0.w, u1.x, u1.y, u1.z, u1.w};
    float fl[8];
    float ds = 0.0f;
#pragma unroll
    for (int t = 0; t < 8; ++t) {
        fl[t] = uu[t] * kv[t] * vm;
        ds = fmaf(cscale * logf(kv[t]), fl[t], ds);
    }
    float4 w0 = {fl[0], fl[1], fl[2], fl[3]};
    float4 w1 = {fl[4], fl[5], fl[6], fl[7]};
    *(float4*)(out + base)     = w0;
    *(float4*)(out + base + 4) = w1;
#pragma unroll
    for (int o = 32; o >= 1; o >>= 1) ds += __shfl_xor(ds, o, 64);
    if (lane == 0) red[tid >> 6] = ds;
    __syncthreads();
    if (tid == 0) atomicAdd(dist, red[0] + red[1] + red[2] + red[3]);
}

// ---------- host ----------
extern "C" void kernel_launch(void* const* d_in, const int* in_sizes, int n_in,
                              void* d_out, int out_size, void* d_ws, size_t ws_size,
                              hipStream_t stream) {
    const float* x = (const float*)d_in[0];
    const float* y = (const float*)d_in[1];
    float* out = (float*)d_out;
    char* ws = (char*)d_ws;

    // workspace layout (total ~147 MB)
    unsigned short* Kmat = (unsigned short*)(ws);                 // 64 MiB (cost, then K in place)
    unsigned short* KT   = (unsigned short*)(ws + 67108864);      // 64 MiB
    unsigned short* xn   = (unsigned short*)(ws + 134217728);     // 8 MiB
    unsigned short* yn   = (unsigned short*)(ws + 142606336);     // 4 MiB
    float* x2            = (float*)(ws + 146800640);
    float* y2            = (float*)(ws + 146833408);
    float* u             = (float*)(ws + 146849792);
    float* v             = (float*)(ws + 146882560);
    unsigned int* maxc   = (unsigned int*)(ws + 146898944);
    float* dist = out + NM;

    init_kernel<<<16, 256, 0, stream>>>(v, maxc, dist);
    rownorm_kernel<<<N_ROWS / 4, 256, 0, stream>>>(x, xn, x2);
    rownorm_kernel<<<M_ROWS / 4, 256, 0, stream>>>(y, yn, y2);
    gemm_cost_kernel<<<dim3(N_ROWS / 128, M_ROWS / 128), 256, 0, stream>>>(xn, yn, x2, y2, Kmat, maxc);
    expT_kernel<<<dim3(N_ROWS / 64, M_ROWS / 64), 256, 0, stream>>>(Kmat, KT, maxc);

    // 100 Sinkhorn iterations as 200 plain launches (launch boundary = grid sync)
    for (int it = 0; it < N_ITERS; ++it) {
        u_step_kernel<<<N_ROWS / 8, 256, 0, stream>>>(Kmat, v, u);
        v_step_kernel<<<M_ROWS / 8, 256, 0, stream>>>(KT, u, v);
    }

    finalize_kernel<<<(unsigned)(NM / (8 * 256)), 256, 0, stream>>>(KT, u, v, maxc, out, dist);
}

// Round 3
// 2750.190 us; speedup vs baseline: 1.1047x; 1.1047x over previous
//
#include <hip/hip_runtime.h>

#define N_ROWS 8192
#define M_ROWS 4096
#define D_DIM  512
#define N_ITERS 100
constexpr size_t NM = (size_t)N_ROWS * (size_t)M_ROWS;
constexpr float FREG   = 0.1f;
constexpr float FI     = 0.5f / (0.5f + 0.1f);     // tau/(tau+reg)
constexpr float A_MARG = 1.0f / (float)N_ROWS;
constexpr float B_MARG = 1.0f / (float)M_ROWS;
#define FIN_BLOCKS 16384                            // NM / (8*256)

// ---------- bf16 helpers (RNE pack) ----------
__device__ __forceinline__ unsigned short f2bf(float f) {
    unsigned int u = __float_as_uint(f);
    u += 0x7fffu + ((u >> 16) & 1u);
    return (unsigned short)(u >> 16);
}
__device__ __forceinline__ float bflo(unsigned int u) { return __uint_as_float(u << 16); }
__device__ __forceinline__ float bfhi(unsigned int u) { return __uint_as_float(u & 0xffff0000u); }
__device__ __forceinline__ unsigned int pack2(float a, float b) {
    return (unsigned int)f2bf(a) | ((unsigned int)f2bf(b) << 16);
}

// ---------- K0: init v = 1/m, maxc = 0 ----------
__global__ void __launch_bounds__(256) init_kernel(float* v, unsigned int* maxc) {
    int t = blockIdx.x * 256 + threadIdx.x;
    if (t < M_ROWS) v[t] = B_MARG;
    if (t == 0) *maxc = 0u;
}

// ---------- K1: per-row min-shift + bf16 cast + sum of squares ----------
__global__ void __launch_bounds__(256) rownorm_kernel(const float* __restrict__ x,
                                                      unsigned short* __restrict__ xn,
                                                      float* __restrict__ x2) {
    int lane = threadIdx.x & 63;
    int row  = blockIdx.x * 4 + (threadIdx.x >> 6);
    const float* p = x + (size_t)row * D_DIM + lane * 8;
    float4 v0 = *(const float4*)p;
    float4 v1 = *(const float4*)(p + 4);
    float a[8] = {v0.x, v0.y, v0.z, v0.w, v1.x, v1.y, v1.z, v1.w};
    float mn = a[0];
#pragma unroll
    for (int t = 1; t < 8; ++t) mn = fminf(mn, a[t]);
#pragma unroll
    for (int o = 32; o >= 1; o >>= 1) mn = fminf(mn, __shfl_xor(mn, o, 64));
    float ss = 0.0f;
#pragma unroll
    for (int t = 0; t < 8; ++t) { a[t] -= mn; ss = fmaf(a[t], a[t], ss); }
#pragma unroll
    for (int o = 32; o >= 1; o >>= 1) ss += __shfl_xor(ss, o, 64);
    uint4 pk;
    pk.x = pack2(a[0], a[1]); pk.y = pack2(a[2], a[3]);
    pk.z = pack2(a[4], a[5]); pk.w = pack2(a[6], a[7]);
    *(uint4*)(xn + (size_t)row * D_DIM + lane * 8) = pk;
    if (lane == 0) x2[row] = ss;
}

// ---------- K2: bf16 MFMA GEMM -> cost (bf16, row-major N x M) + global max ----------
typedef __attribute__((ext_vector_type(8))) short short8;   // 8 bf16 = 4 VGPRs
typedef __attribute__((ext_vector_type(4))) float f32x4;

__global__ void __launch_bounds__(256) gemm_cost_kernel(const unsigned short* __restrict__ xn,
                                                        const unsigned short* __restrict__ yn,
                                                        const float* __restrict__ x2,
                                                        const float* __restrict__ y2,
                                                        unsigned short* __restrict__ cost,
                                                        unsigned int* __restrict__ maxc) {
    // 128x128 block tile, 4 waves in 2x2, each wave 64x64 via 4x4 MFMA 16x16x32
    __shared__ unsigned short As[128 * 40];   // pad 32->40 to break bank conflicts
    __shared__ unsigned short Bs[128 * 40];
    __shared__ float wred[4];
    int tid = threadIdx.x, lane = tid & 63, w = tid >> 6;
    int wm = w >> 1, wn = w & 1;
    int i0 = blockIdx.x * 128, j0 = blockIdx.y * 128;
    int lr = tid >> 2;      // 0..63 (staging row)
    int lq = tid & 3;       // 0..3  (staging col group of 8)
    f32x4 acc[4][4] = {};
    int m = lane & 15, quad = lane >> 4;

    for (int k0 = 0; k0 < D_DIM; k0 += 32) {
        uint4 a0 = *(const uint4*)(xn + (size_t)(i0 + lr) * D_DIM + k0 + lq * 8);
        uint4 a1 = *(const uint4*)(xn + (size_t)(i0 + lr + 64) * D_DIM + k0 + lq * 8);
        uint4 b0 = *(const uint4*)(yn + (size_t)(j0 + lr) * D_DIM + k0 + lq * 8);
        uint4 b1 = *(const uint4*)(yn + (size_t)(j0 + lr + 64) * D_DIM + k0 + lq * 8);
        __syncthreads();
        *(uint4*)&As[lr * 40 + lq * 8]        = a0;
        *(uint4*)&As[(lr + 64) * 40 + lq * 8] = a1;
        *(uint4*)&Bs[lr * 40 + lq * 8]        = b0;
        *(uint4*)&Bs[(lr + 64) * 40 + lq * 8] = b1;
        __syncthreads();
        short8 af[4], bfr[4];
#pragma unroll
        for (int t = 0; t < 4; ++t) {
            af[t]  = *(const short8*)&As[(wm * 64 + t * 16 + m) * 40 + quad * 8];
            bfr[t] = *(const short8*)&Bs[(wn * 64 + t * 16 + m) * 40 + quad * 8];
        }
#pragma unroll
        for (int tm = 0; tm < 4; ++tm)
#pragma unroll
            for (int tn = 0; tn < 4; ++tn)
                acc[tm][tn] = __builtin_amdgcn_mfma_f32_16x16x32_bf16(af[tm], bfr[tn], acc[tm][tn], 0, 0, 0);
    }

    // epilogue: C/D layout col=lane&15, row=(lane>>4)*4+reg  [m89/m91 verified]
    float mymax = 0.0f;
#pragma unroll
    for (int tm = 0; tm < 4; ++tm) {
#pragma unroll
        for (int tn = 0; tn < 4; ++tn) {
            int col = j0 + wn * 64 + tn * 16 + m;
            float yv = y2[col];
#pragma unroll
            for (int t = 0; t < 4; ++t) {
                int row = i0 + wm * 64 + tm * 16 + quad * 4 + t;
                float c = fmaxf(x2[row] + yv - 2.0f * acc[tm][tn][t], 0.0f);
                mymax = fmaxf(mymax, c);
                cost[(size_t)row * M_ROWS + col] = f2bf(c);
            }
        }
    }
#pragma unroll
    for (int o = 32; o >= 1; o >>= 1) mymax = fmaxf(mymax, __shfl_xor(mymax, o, 64));
    if (lane == 0) wred[w] = mymax;
    __syncthreads();
    if (tid == 0) {
        float mx = fmaxf(fmaxf(wred[0], wred[1]), fmaxf(wred[2], wred[3]));
        atomicMax(maxc, __float_as_uint(mx));   // positive floats: uint order == float order
    }
}

// ---------- K3: K = exp(-cost*10/maxc) in place (bf16) + transposed copy KT ----------
__global__ void __launch_bounds__(256) expT_kernel(unsigned short* __restrict__ Kmat,
                                                   unsigned short* __restrict__ KTmat,
                                                   const unsigned int* __restrict__ maxcb) {
    __shared__ unsigned int tl[64 * 33];
    float scale = -(1.0f / FREG) / __uint_as_float(*maxcb);
    int i0 = blockIdx.x * 64, j0 = blockIdx.y * 64;
    int tid = threadIdx.x;
    int b = tid & 7;        // col group (8 cols)
    int rp = tid >> 3;      // 0..31 row pair
    size_t base0 = (size_t)(i0 + 2 * rp) * M_ROWS + j0 + b * 8;
    uint4 c0 = *(const uint4*)(Kmat + base0);
    uint4 c1 = *(const uint4*)(Kmat + base0 + M_ROWS);
    unsigned int cc0[4] = {c0.x, c0.y, c0.z, c0.w};
    unsigned int cc1[4] = {c1.x, c1.y, c1.z, c1.w};
    float k0[8], k1[8];
#pragma unroll
    for (int t = 0; t < 4; ++t) {
        k0[2 * t]     = expf(bflo(cc0[t]) * scale);
        k0[2 * t + 1] = expf(bfhi(cc0[t]) * scale);
        k1[2 * t]     = expf(bflo(cc1[t]) * scale);
        k1[2 * t + 1] = expf(bfhi(cc1[t]) * scale);
    }
    uint4 o0, o1;
    o0.x = pack2(k0[0], k0[1]); o0.y = pack2(k0[2], k0[3]);
    o0.z = pack2(k0[4], k0[5]); o0.w = pack2(k0[6], k0[7]);
    o1.x = pack2(k1[0], k1[1]); o1.y = pack2(k1[2], k1[3]);
    o1.z = pack2(k1[4], k1[5]); o1.w = pack2(k1[6], k1[7]);
    *(uint4*)(Kmat + base0)          = o0;   // in-place: tile-private addresses
    *(uint4*)(Kmat + base0 + M_ROWS) = o1;
#pragma unroll
    for (int t = 0; t < 8; ++t)
        tl[(b * 8 + t) * 33 + rp] = pack2(k0[t], k1[t]);  // T[c][row-pair], lo=even row
    __syncthreads();
    int c = tid >> 2, q = tid & 3;
    unsigned int o[8];
#pragma unroll
    for (int k = 0; k < 8; ++k) o[k] = tl[c * 33 + q * 8 + k];
    uint4 w0 = {o[0], o[1], o[2], o[3]};
    uint4 w1 = {o[4], o[5], o[6], o[7]};
    size_t ob = (size_t)(j0 + c) * N_ROWS + i0 + q * 16;
    *(uint4*)(KTmat + ob)     = w0;
    *(uint4*)(KTmat + ob + 8) = w1;
}

// ---------- K4a: u = (a / (K v))^fi.  1 row per wave, no LDS (v is L1-resident),
// uint4 K loads, 4 independent accumulators to break the fma dependency chain. ----------
__global__ void __launch_bounds__(256) u_step_kernel(const unsigned short* __restrict__ Km,
                                                     const float* __restrict__ v,
                                                     float* __restrict__ u) {
    int tid = threadIdx.x, lane = tid & 63, w = tid >> 6;
    int r = blockIdx.x * 4 + w;
    const unsigned short* kp = Km + (size_t)r * M_ROWS + lane * 8;
    const float* vp = v + lane * 8;
    float a0 = 0.0f, a1 = 0.0f, a2 = 0.0f, a3 = 0.0f;
#pragma unroll
    for (int s = 0; s < 8; ++s) {
        uint4 kk = *(const uint4*)(kp + s * 512);
        float4 v0 = *(const float4*)(vp + s * 512);
        float4 v1 = *(const float4*)(vp + s * 512 + 4);
        a0 = fmaf(bflo(kk.x), v0.x, a0);
        a1 = fmaf(bfhi(kk.x), v0.y, a1);
        a2 = fmaf(bflo(kk.y), v0.z, a2);
        a3 = fmaf(bfhi(kk.y), v0.w, a3);
        a0 = fmaf(bflo(kk.z), v1.x, a0);
        a1 = fmaf(bfhi(kk.z), v1.y, a1);
        a2 = fmaf(bflo(kk.w), v1.z, a2);
        a3 = fmaf(bfhi(kk.w), v1.w, a3);
    }
    float dot = (a0 + a1) + (a2 + a3);
#pragma unroll
    for (int o = 32; o >= 1; o >>= 1) dot += __shfl_xor(dot, o, 64);
    if (lane == 0) u[r] = powf(A_MARG / dot, FI);
}

// ---------- K4b: v = (b / (K^T u))^fi ----------
__global__ void __launch_bounds__(256) v_step_kernel(const unsigned short* __restrict__ KTm,
                                                     const float* __restrict__ u,
                                                     float* __restrict__ v) {
    int tid = threadIdx.x, lane = tid & 63, w = tid >> 6;
    int r = blockIdx.x * 4 + w;
    const unsigned short* kp = KTm + (size_t)r * N_ROWS + lane * 8;
    const float* up = u + lane * 8;
    float a0 = 0.0f, a1 = 0.0f, a2 = 0.0f, a3 = 0.0f;
#pragma unroll
    for (int s = 0; s < 16; ++s) {
        uint4 kk = *(const uint4*)(kp + s * 512);
        float4 v0 = *(const float4*)(up + s * 512);
        float4 v1 = *(const float4*)(up + s * 512 + 4);
        a0 = fmaf(bflo(kk.x), v0.x, a0);
        a1 = fmaf(bfhi(kk.x), v0.y, a1);
        a2 = fmaf(bflo(kk.y), v0.z, a2);
        a3 = fmaf(bfhi(kk.y), v0.w, a3);
        a0 = fmaf(bflo(kk.z), v1.x, a0);
        a1 = fmaf(bfhi(kk.z), v1.y, a1);
        a2 = fmaf(bflo(kk.w), v1.z, a2);
        a3 = fmaf(bfhi(kk.w), v1.w, a3);
    }
    float dot = (a0 + a1) + (a2 + a3);
#pragma unroll
    for (int o = 32; o >= 1; o >>= 1) dot += __shfl_xor(dot, o, 64);
    if (lane == 0) v[r] = powf(B_MARG / dot, FI);
}

// ---------- K5: pi = flow^T (KT layout, coalesced), per-block dist partials ----------
__global__ void __launch_bounds__(256) finalize_kernel(const unsigned short* __restrict__ KTm,
                                                       const float* __restrict__ u,
                                                       const float* __restrict__ v,
                                                       const unsigned int* __restrict__ maxcb,
                                                       float* __restrict__ out,
                                                       float* __restrict__ part) {
    __shared__ float red[4];
    int tid = threadIdx.x, lane = tid & 63;
    size_t base = ((size_t)blockIdx.x * 256 + tid) * 8;
    int mrow = (int)(base >> 13);        // / 8192
    int n    = (int)(base & 8191);
    float cscale = -FREG * __uint_as_float(*maxcb);   // cost = -reg*maxc*ln(K)
    uint4 kk = *(const uint4*)(KTm + base);
    float4 u0 = *(const float4*)(u + n);
    float4 u1 = *(const float4*)(u + n + 4);
    float vm = v[mrow];
    float kv[8] = {bflo(kk.x), bfhi(kk.x), bflo(kk.y), bfhi(kk.y),
                   bflo(kk.z), bfhi(kk.z), bflo(kk.w), bfhi(kk.w)};
    float uu[8] = {u0.x, u0.y, u0.z, u0.w, u1.x, u1.y, u1.z, u1.w};
    float fl[8];
    float ds = 0.0f;
#pragma unroll
    for (int t = 0; t < 8; ++t) {
        fl[t] = uu[t] * kv[t] * vm;
        ds = fmaf(cscale * logf(kv[t]), fl[t], ds);
    }
    float4 w0 = {fl[0], fl[1], fl[2], fl[3]};
    float4 w1 = {fl[4], fl[5], fl[6], fl[7]};
    *(float4*)(out + base)     = w0;
    *(float4*)(out + base + 4) = w1;
#pragma unroll
    for (int o = 32; o >= 1; o >>= 1) ds += __shfl_xor(ds, o, 64);
    if (lane == 0) red[tid >> 6] = ds;
    __syncthreads();
    if (tid == 0) part[blockIdx.x] = red[0] + red[1] + red[2] + red[3];
}

// ---------- K6: reduce 16384 partials -> dist (no atomics) ----------
__global__ void __launch_bounds__(256) reduce_dist_kernel(const float* __restrict__ part,
                                                          float* __restrict__ dist) {
    __shared__ float red[4];
    int tid = threadIdx.x, lane = tid & 63;
    float s = 0.0f;
    for (int i = tid; i < FIN_BLOCKS; i += 256) s += part[i];
#pragma unroll
    for (int o = 32; o >= 1; o >>= 1) s += __shfl_xor(s, o, 64);
    if (lane == 0) red[tid >> 6] = s;
    __syncthreads();
    if (tid == 0) *dist = red[0] + red[1] + red[2] + red[3];
}

// ---------- host ----------
extern "C" void kernel_launch(void* const* d_in, const int* in_sizes, int n_in,
                              void* d_out, int out_size, void* d_ws, size_t ws_size,
                              hipStream_t stream) {
    const float* x = (const float*)d_in[0];
    const float* y = (const float*)d_in[1];
    float* out = (float*)d_out;
    char* ws = (char*)d_ws;

    // workspace layout (total ~140 MB)
    unsigned short* Kmat = (unsigned short*)(ws);                 // 64 MiB (cost, then K in place)
    unsigned short* KT   = (unsigned short*)(ws + 67108864);      // 64 MiB
    unsigned short* xn   = (unsigned short*)(ws + 134217728);     // 8 MiB (dead after gemm)
    unsigned short* yn   = (unsigned short*)(ws + 142606336);     // 4 MiB
    float* x2            = (float*)(ws + 146800640);
    float* y2            = (float*)(ws + 146833408);
    float* u             = (float*)(ws + 146849792);
    float* v             = (float*)(ws + 146882560);
    unsigned int* maxc   = (unsigned int*)(ws + 146898944);
    float* part          = (float*)(ws + 134217728);              // reuse dead xn region (64 KB)
    float* dist = out + NM;

    init_kernel<<<16, 256, 0, stream>>>(v, maxc);
    rownorm_kernel<<<N_ROWS / 4, 256, 0, stream>>>(x, xn, x2);
    rownorm_kernel<<<M_ROWS / 4, 256, 0, stream>>>(y, yn, y2);
    gemm_cost_kernel<<<dim3(N_ROWS / 128, M_ROWS / 128), 256, 0, stream>>>(xn, yn, x2, y2, Kmat, maxc);
    expT_kernel<<<dim3(N_ROWS / 64, M_ROWS / 64), 256, 0, stream>>>(Kmat, KT, maxc);

    // 100 Sinkhorn iterations as 200 plain launches (launch boundary = grid sync)
    for (int it = 0; it < N_ITERS; ++it) {
        u_step_kernel<<<N_ROWS / 4, 256, 0, stream>>>(Kmat, v, u);
        v_step_kernel<<<M_ROWS / 4, 256, 0, stream>>>(KT, u, v);
    }

    finalize_kernel<<<FIN_BLOCKS, 256, 0, stream>>>(KT, u, v, maxc, out, part);
    reduce_dist_kernel<<<1, 256, 0, stream>>>(part, dist);
}